// Round 12
// baseline (205.889 us; speedup 1.0000x reference)
//
#include <hip/hip_runtime.h>
#include <math.h>

#define NEGC (-1000.0f)
#define MAGICA 0x5137A9C1u
#define MAGICB 0x2468ACE1u
#define MAGICC 0x13579BDFu
#define MAGICD 0x0F1E2D3Cu

// One kernel, 256 blocks x 512 threads, all co-resident (256 blocks <= 256 CUs).
// blocks 0..135 : GEMM A2/B2 -> flag sync -> (0..127) phase B tile -> tile flag
// blocks 136..255: zero adj concurrently -> zero flag; block 255 then runs the
//                  DP on wave 0, gated per 128-s window by the 8 tile flags.
__global__ __launch_bounds__(512, 1) void kall(
    const float* __restrict__ seg, const float* __restrict__ vid,
    const float* __restrict__ W1, const float* __restrict__ b1,
    const float* __restrict__ W2, const float* __restrict__ b2p,
    float* __restrict__ A2, float* __restrict__ B2,
    float* __restrict__ logitsT, float* __restrict__ lsPK,
    float* __restrict__ out, unsigned* __restrict__ flags)
{
    // flags[0..135]=GEMM done; [200]=broadcast; [256+b]=tile b done; [384+bid]=zero done
    __shared__ __align__(16) char smem[33280];
    const int bid = blockIdx.x;
    const int tid = threadIdx.x;

    if (bid < 136) {
        auto Xs = (float (*)[64])smem;              // [kk][row] / As
        auto Ws = (float (*)[64])(smem + 8192);     // [kk][col] / Bs
        float* w2s = (float*)(smem + 16384);
        const int tx = tid & 15;        // 0..15
        const int ty = tid >> 4;        // 0..31
        const int lr8 = tid >> 3;       // 0..63
        const int lk8 = (tid & 7) * 4;  // 0,4,..,28

        // ---- Phase A: GEMM (2x4 outputs/thread, register-prefetched) ----
        {
            const int colBase = (bid & 3) * 64;
            const int rowBase = (bid >> 2) * 64;
            const bool isSeg = (rowBase < 128);
            const float* __restrict__ X = isSeg ? seg : vid;
            const int xRow = isSeg ? rowBase : (rowBase - 128);
            const int wOff = isSeg ? 0 : 512;

            float acc[2][4] = {};
            float4 xa = *(const float4*)(X + (size_t)(xRow + lr8) * 512 + lk8);
            float4 wa = *(const float4*)(W1 + (size_t)(colBase + lr8) * 1024 + (wOff + lk8));

            for (int k0 = 0; k0 < 512; k0 += 32) {
                __syncthreads();
                Xs[lk8 + 0][lr8] = xa.x; Xs[lk8 + 1][lr8] = xa.y;
                Xs[lk8 + 2][lr8] = xa.z; Xs[lk8 + 3][lr8] = xa.w;
                Ws[lk8 + 0][lr8] = wa.x; Ws[lk8 + 1][lr8] = wa.y;
                Ws[lk8 + 2][lr8] = wa.z; Ws[lk8 + 3][lr8] = wa.w;
                __syncthreads();
                if (k0 + 32 < 512) {
                    xa = *(const float4*)(X + (size_t)(xRow + lr8) * 512 + (k0 + 32 + lk8));
                    wa = *(const float4*)(W1 + (size_t)(colBase + lr8) * 1024 + (wOff + k0 + 32 + lk8));
                }
                #pragma unroll
                for (int kk = 0; kk < 32; ++kk) {
                    const float2 a2 = *(const float2*)&Xs[kk][2 * ty];
                    const float4 b4 = *(const float4*)&Ws[kk][4 * tx];
                    const float* a = (const float*)&a2;
                    const float* b = (const float*)&b4;
                    #pragma unroll
                    for (int i = 0; i < 2; ++i)
                        #pragma unroll
                        for (int j = 0; j < 4; ++j)
                            acc[i][j] = fmaf(a[i], b[j], acc[i][j]);
                }
            }

            float* __restrict__ outp = (isSeg ? A2 : B2) + (size_t)xRow * 256;
            const int c = colBase + 4 * tx;
            #pragma unroll
            for (int i = 0; i < 2; ++i) {
                float4 v = make_float4(acc[i][0], acc[i][1], acc[i][2], acc[i][3]);
                if (isSeg) {
                    v.x += b1[c + 0]; v.y += b1[c + 1]; v.z += b1[c + 2]; v.w += b1[c + 3];
                }
                *(float4*)(outp + (size_t)(2 * ty + i) * 256 + c) = v;
            }
        }

        // ---- flag sync (R10/R11-proven shape) ----
        __syncthreads();
        if (tid == 0)
            __hip_atomic_store(&flags[bid], MAGICA, __ATOMIC_RELEASE, __HIP_MEMORY_SCOPE_AGENT);
        if (bid == 0) {
            if (tid < 136) {
                while (__hip_atomic_load(&flags[tid], __ATOMIC_ACQUIRE,
                                         __HIP_MEMORY_SCOPE_AGENT) != MAGICA)
                    __builtin_amdgcn_s_sleep(2);
            }
            __syncthreads();
            if (tid == 0)
                __hip_atomic_store(&flags[200], MAGICB, __ATOMIC_RELEASE, __HIP_MEMORY_SCOPE_AGENT);
        }
        if (bid >= 128) return;
        if (tid == 0) {
            while (__hip_atomic_load(&flags[200], __ATOMIC_ACQUIRE,
                                     __HIP_MEMORY_SCOPE_AGENT) != MAGICB)
                __builtin_amdgcn_s_sleep(2);
        }
        __syncthreads();

        // ---- Phase B: 64n x 32s tile, 2x2 outputs/thread (R11-proven) ----
        {
            const int nBase = (bid & 1) * 64;
            const int sBase = (bid >> 1) * 32;
            if (tid < 256) w2s[tid] = W2[tid];
            const float b2v = b2p[0];

            float acc[2][2] = {};   // [i:n][j:s]
            float4 aa = *(const float4*)(A2 + (size_t)(nBase + lr8) * 256 + lk8);
            float4 ba;
            if (tid < 256) ba = *(const float4*)(B2 + (size_t)(sBase + lr8) * 256 + lk8);

            for (int k0 = 0; k0 < 256; k0 += 32) {
                __syncthreads();
                Xs[lk8 + 0][lr8] = aa.x; Xs[lk8 + 1][lr8] = aa.y;
                Xs[lk8 + 2][lr8] = aa.z; Xs[lk8 + 3][lr8] = aa.w;
                if (tid < 256) {
                    Ws[lk8 + 0][lr8] = ba.x; Ws[lk8 + 1][lr8] = ba.y;
                    Ws[lk8 + 2][lr8] = ba.z; Ws[lk8 + 3][lr8] = ba.w;
                }
                __syncthreads();
                if (k0 + 32 < 256) {
                    aa = *(const float4*)(A2 + (size_t)(nBase + lr8) * 256 + (k0 + 32 + lk8));
                    if (tid < 256)
                        ba = *(const float4*)(B2 + (size_t)(sBase + lr8) * 256 + (k0 + 32 + lk8));
                }
                #pragma unroll
                for (int kk = 0; kk < 32; ++kk) {
                    const float w = w2s[k0 + kk];
                    const float2 a2 = *(const float2*)&Xs[kk][2 * ty];
                    const float2 b2 = *(const float2*)&Ws[kk][2 * tx];
                    const float* a = (const float*)&a2;
                    const float* b = (const float*)&b2;
                    #pragma unroll
                    for (int i = 0; i < 2; ++i)
                        #pragma unroll
                        for (int j = 0; j < 2; ++j)
                            acc[i][j] = fmaf(fmaxf(a[i] + b[j], 0.0f), w, acc[i][j]);
                }
            }

            const int nb = nBase + 2 * ty;          // even
            const int s0 = sBase + 2 * tx;          // even
            float lsv[2][2];                        // [j:s][i:n]
            #pragma unroll
            for (int j = 0; j < 2; ++j) {
                float2 lg;
                float* lgp = (float*)&lg;
                #pragma unroll
                for (int i = 0; i < 2; ++i) {
                    const float x = acc[i][j] + b2v;
                    lgp[i] = x;
                    lsv[j][i] = fminf(x, 0.0f) - log1pf(expf(-fabsf(x)));
                }
                *(float2*)&logitsT[(size_t)(s0 + j) * 128 + nb] = lg;
            }
            float4 pk = make_float4(lsv[0][0], lsv[1][0], lsv[0][1], lsv[1][1]);
            *(float4*)&lsPK[(size_t)(s0 / 2) * 256 + 2 * nb] = pk;
        }
        __syncthreads();
        if (tid == 0)
            __hip_atomic_store(&flags[256 + bid], MAGICD, __ATOMIC_RELEASE, __HIP_MEMORY_SCOPE_AGENT);
        return;
    }

    // ================= zero blocks (136..255) =================
    {
        float4* out4 = (float4*)out;
        const float4 z = make_float4(0.f, 0.f, 0.f, 0.f);
        const int start = (bid - 136) * 9865;
        const int end = (start + 9865 < 1183744) ? start + 9865 : 1183744;
        for (int i = start + tid; i < end; i += 512) out4[i] = z;
        __syncthreads();
        if (tid == 0)
            __hip_atomic_store(&flags[384 + bid], MAGICC, __ATOMIC_RELEASE, __HIP_MEMORY_SCOPE_AGENT);
        if (bid != 255) return;
    }
    if (tid >= 64) return;

    // ================= DP (block 255, wave 0; R6/R11-proven body + window gates) =================
    {
        unsigned* takeW = (unsigned*)smem;          // [n][wordIdx], 65-pad (33280 B)
        const int lane = tid;
        const int n0 = 2 * lane, n1 = n0 + 1;
        const float4* __restrict__ ls4 = (const float4*)lsPK;

        float p0 = NEGC, p1 = NEGC;
        unsigned u0 = 2047u - (unsigned)n0;   // s - n0 (head phase)
        unsigned u1 = u0 - 1u;                // s - n1
        unsigned w0 = 0u, w1 = 0u;

        auto core = [&](float lx, float ly, float nx) {
            float c0, c1;
            unsigned long long cc;
            asm volatile(
                "v_add_f32 %[c0], %[lx], %[p1]\n\t"
                "v_add_f32 %[c1], %[ly], %[nx]\n\t"
                "v_cmp_ge_f32 vcc, %[c0], %[p0]\n\t"
                "v_cmp_ge_f32 %[cc], %[c1], %[p1]\n\t"
                "v_addc_co_u32 %[w0], vcc, %[w0], %[w0], vcc\n\t"
                "v_addc_co_u32 %[w1], %[cc], %[w1], %[w1], %[cc]\n\t"
                "v_max_f32 %[p0], %[c0], %[p0]\n\t"
                "v_max_f32 %[p1], %[c1], %[p1]\n\t"
                : [p0]"+v"(p0), [p1]"+v"(p1), [w0]"+v"(w0), [w1]"+v"(w1),
                  [c0]"=&v"(c0), [c1]"=&v"(c1), [cc]"=&s"(cc)
                : [lx]"v"(lx), [ly]"v"(ly), [nx]"v"(nx)
                : "vcc");
        };

        auto stepF = [&](float lx, float ly) { // in-band
            float nxt1 = __int_as_float(__builtin_amdgcn_update_dpp(
                0, __float_as_int(p0), 0x130 /*WAVE_SHL1*/, 0xf, 0xf, true));
            core(lx, ly, nxt1);
        };
        auto stepM = [&](float lx, float ly) { // masked (head/tail)
            float nxt1 = __int_as_float(__builtin_amdgcn_update_dpp(
                0, __float_as_int(p0), 0x130, 0xf, 0xf, true));
            core(lx, ly, nxt1);
            p0 = (u0 <= 1920u) ? p0 : NEGC;   // 0 <= s-n <= 1920 (wrap covers s<n)
            p1 = (u1 <= 1920u) ? p1 : NEGC;
            --u0; --u1;
        };

        // wait for the 8 phase-B tiles covering window g (bids 120-8g..127-8g)
        auto waitWin = [&](int g) {
            const unsigned* tf = &flags[256 + 120 - 8 * g];
            while (__hip_atomic_load(&tf[lane & 7], __ATOMIC_ACQUIRE,
                                     __HIP_MEMORY_SCOPE_AGENT) != MAGICD)
                __builtin_amdgcn_s_sleep(2);
        };

        float4 B0[4], B1[4], B2r[4], B3[4], B4[4], B5[4], B6[4], B7[4];
        int wIdx = 63;
#define LOADG(B, H) { _Pragma("unroll") \
    for (int j = 0; j < 4; ++j) B[j] = ls4[(size_t)((1023 - 4 * (H) - j) * 64 + lane)]; }
#define STEPS_F(B) { _Pragma("unroll") \
    for (int j = 0; j < 4; ++j) { stepF(B[j].y, B[j].w); stepF(B[j].x, B[j].z); } }
#define STEPS_M(B) { _Pragma("unroll") \
    for (int j = 0; j < 4; ++j) { stepM(B[j].y, B[j].w); stepM(B[j].x, B[j].z); } }
#define FLUSH { takeW[n0 * 65 + wIdx] = w0; takeW[n1 * 65 + wIdx] = w1; \
                w0 = 0u; w1 = 0u; --wIdx; }
#define BODY(SM) \
    SM(B0);  if (h +  8 < 256) LOADG(B0,  h +  8); \
    SM(B1);  if (h +  9 < 256) LOADG(B1,  h +  9); \
    SM(B2r); if (h + 10 < 256) LOADG(B2r, h + 10); \
    SM(B3);  FLUSH; if (h + 11 < 256) LOADG(B3, h + 11); \
    SM(B4);  if (h + 12 < 256) LOADG(B4,  h + 12); \
    SM(B5);  if (h + 13 < 256) LOADG(B5,  h + 13); \
    SM(B6);  if (h + 14 < 256) LOADG(B6,  h + 14); \
    SM(B7);  FLUSH; if (h + 15 < 256) LOADG(B7, h + 15);
#define GATE { int gw = (h + 15) >> 4; if (gw > 15) gw = 15; waitWin(gw); }

        waitWin(0);
        LOADG(B0, 0) LOADG(B1, 1) LOADG(B2r, 2) LOADG(B3, 3)
        LOADG(B4, 4) LOADG(B5, 5) LOADG(B6, 6) LOADG(B7, 7)
        // head: sub-groups 0..15 (s 2047..1920) — masked
        for (int h = 0; h < 16; h += 8) { GATE BODY(STEPS_M) }
        // mid: sub-groups 16..239 (s 1919..128) — in-band
        for (int h = 16; h < 240; h += 8) { GATE BODY(STEPS_F) }
        // tail: sub-groups 240..255 (s 127..0) — masked; reset u = s - n at s=127
        u0 = (unsigned)(127 - n0);
        u1 = u0 - 1u;
        for (int h = 240; h < 256; h += 8) { GATE BODY(STEPS_M) }
#undef GATE
#undef BODY
#undef FLUSH
#undef STEPS_M
#undef STEPS_F
#undef LOADG

        // wave-parallel walk (single wave; per-wave DS ordering suffices)
        int a0r = 0, a1r = 0, pos = 0;
        for (int n = 0; n < 128; ++n) {
            unsigned w = takeW[n * 65 + lane];
            const int wi0 = pos >> 5;
            if (lane < wi0) w = 0u;
            else if (lane == wi0) w &= (0xFFFFFFFFu << (pos & 31));
            const unsigned long long m = __ballot(w != 0u);
            if (m == 0ull) break;               // uniform
            const int fl = __builtin_ctzll(m);
            const unsigned fw = (unsigned)__builtin_amdgcn_readlane((int)w, fl);
            const int s = fl * 32 + __builtin_ctz(fw);  // wave-uniform
            if (n == n0) a0r = s;
            if (n == n1) a1r = s;
            pos = s + 1;
        }

        // wait for all zero blocks (finished long ago), then write outputs
        #pragma unroll
        for (int r = 0; r < 2; ++r) {
            const int idx = 136 + r * 64 + lane;
            if (idx <= 255) {
                while (__hip_atomic_load(&flags[384 + idx], __ATOMIC_ACQUIRE,
                                         __HIP_MEMORY_SCOPE_AGENT) != MAGICC)
                    __builtin_amdgcn_s_sleep(2);
            }
        }

        out[(size_t)(2048 + n0) * 2176 + a0r] = 1.0f;
        out[(size_t)(2048 + n1) * 2176 + a1r] = 1.0f;
        float sum = logitsT[(size_t)a0r * 128 + n0] + logitsT[(size_t)a1r * 128 + n1];
        #pragma unroll
        for (int off = 32; off >= 1; off >>= 1) sum += __shfl_down(sum, off);
        if (lane == 0) out[(size_t)2176 * 2176] = sum * (1.0f / 128.0f);
    }
}

extern "C" void kernel_launch(void* const* d_in, const int* in_sizes, int n_in,
                              void* d_out, int out_size, void* d_ws, size_t ws_size,
                              hipStream_t stream)
{
    const float* seg = (const float*)d_in[0];   // [128][512]
    const float* vid = (const float*)d_in[1];   // [2048][512]
    const float* W1  = (const float*)d_in[2];   // [256][1024]
    const float* b1  = (const float*)d_in[3];   // [256]
    const float* W2  = (const float*)d_in[4];   // [256]
    const float* b2  = (const float*)d_in[5];   // [1]
    float* out = (float*)d_out;
    float* ws  = (float*)d_ws;

    float* A2      = ws;             // 128*256
    float* B2      = ws + 32768;     // 2048*256
    float* logitsT = ws + 557056;    // 2048*128, [s][n]
    float* lsPK    = ws + 819200;    // 2048*128 packed [s/2][n][2]
    unsigned* flags = (unsigned*)(ws + 1081344);  // 640 words; MAGICs != 0xAA poison

    kall<<<dim3(256), dim3(512), 0, stream>>>(seg, vid, W1, b1, W2, b2,
                                              A2, B2, logitsT, lsPK, out, flags);
}